// Round 2
// baseline (45295.618 us; speedup 1.0000x reference)
//
#include <hip/hip_runtime.h>
#include <math.h>

#define NB 32
#define NN 32
#define NSTEPS 600
#define NT1 601
#define NSI 10
#define NH 75

#define ICM2IFS 2.99792458e-05
#define KBOLTZ 0.6950389f
#define TWO_PI 6.283185307179586476925286766559

__device__ __forceinline__ float elu1(float x) { return x > 0.f ? x : expm1f(x); }

// ---------------------------------------------------------------------------
// Phase A: batched 32x32 symmetric eigensolver (parallel cyclic Jacobi), FP64.
// One block (1 wave, 64 threads) per matrix. A and V padded to 33 columns.
// FP64 so our eigenvectors converge to truth (~1e-10); the reference's own
// eigh rounding then dominates the residual mismatch.
// ---------------------------------------------------------------------------
__global__ __launch_bounds__(64) void eigh_kernel(const float* __restrict__ Hf,
                                                  float* __restrict__ E_all,
                                                  float* __restrict__ CT_all)
{
    __shared__ double A[NN][NN + 1];
    __shared__ double V[NN][NN + 1];
    __shared__ double csC[16], csS[16];
    __shared__ int   prC[16], qrC[16];
    __shared__ double redv;
    __shared__ int   rankl[NN];

    const int idx = blockIdx.x;      // b*601 + t
    const int tid = threadIdx.x;
    const float* Hp = Hf + (size_t)idx * (NN * NN);

    for (int e = tid; e < NN * NN; e += 64) {
        A[e >> 5][e & 31] = (double)Hp[e];
        V[e >> 5][e & 31] = ((e >> 5) == (e & 31)) ? 1.0 : 0.0;
    }
    __syncthreads();

    double part = 0.0;
    for (int e = tid; e < NN * NN; e += 64) { double v = A[e >> 5][e & 31]; part += v * v; }
    #pragma unroll
    for (int off = 32; off > 0; off >>= 1) part += __shfl_down(part, off);
    if (tid == 0) redv = part;
    __syncthreads();
    const double tol2 = 1e-26 * redv;

    for (int sweep = 0; sweep < 30; ++sweep) {
        for (int r = 0; r < NN - 1; ++r) {
            // round-robin tournament pairing: player 0 fixed, 1..31 rotate
            if (tid < 16) {
                int m = tid, p, q;
                if (m == 0) { p = 0; q = 1 + (r % 31); }
                else { p = 1 + ((m + r) % 31); q = 1 + ((31 - m + r) % 31); }
                double apq = A[p][q];
                double c = 1.0, sn = 0.0;
                if (apq != 0.0) {
                    double theta = 0.5 * (A[q][q] - A[p][p]) / apq;
                    double tt = 1.0 / (fabs(theta) + sqrt(theta * theta + 1.0));
                    if (theta < 0.0) tt = -tt;
                    c = 1.0 / sqrt(tt * tt + 1.0);
                    sn = tt * c;
                }
                csC[m] = c; csS[m] = sn; prC[m] = p; qrC[m] = q;
            }
            __syncthreads();
            // row phase: A <- J^T A   (disjoint rows across the 16 pairs)
            #pragma unroll
            for (int it = 0; it < 8; ++it) {
                int task = tid + it * 64;
                int m = task >> 5, jc = task & 31;
                int p = prC[m], q = qrC[m];
                double c = csC[m], sn = csS[m];
                double ap = A[p][jc], aq = A[q][jc];
                A[p][jc] = c * ap - sn * aq;
                A[q][jc] = sn * ap + c * aq;
            }
            __syncthreads();
            // col phase: A <- A J, V <- V J  (disjoint cols across pairs)
            #pragma unroll
            for (int it = 0; it < 16; ++it) {
                int task = tid + it * 64;
                int m = (task >> 5) & 15, ir = task & 31;
                int p = prC[m], q = qrC[m];
                double c = csC[m], sn = csS[m];
                if (task < 512) {
                    double aip = A[ir][p], aiq = A[ir][q];
                    A[ir][p] = c * aip - sn * aiq;
                    A[ir][q] = sn * aip + c * aiq;
                } else {
                    double vip = V[ir][p], viq = V[ir][q];
                    V[ir][p] = c * vip - sn * viq;
                    V[ir][q] = sn * vip + c * viq;
                }
            }
            __syncthreads();
        }
        double o = 0.0;
        for (int e = tid; e < NN * NN; e += 64) {
            int i2 = e >> 5, j2 = e & 31;
            double v = A[i2][j2];
            o += (i2 != j2) ? v * v : 0.0;
        }
        #pragma unroll
        for (int off = 32; off > 0; off >>= 1) o += __shfl_down(o, off);
        if (tid == 0) redv = o;
        __syncthreads();
        if (redv <= tol2) break;
    }
    __syncthreads();

    // sort ascending (ties broken by index) and emit CT (eigenvectors as rows)
    if (tid < NN) {
        double ei = A[tid][tid];
        int rk = 0;
        for (int j2 = 0; j2 < NN; ++j2) {
            double ej = A[j2][j2];
            rk += (ej < ei || (ej == ei && j2 < tid)) ? 1 : 0;
        }
        rankl[tid] = rk;
        E_all[(size_t)idx * NN + rk] = (float)ei;
    }
    __syncthreads();
    float* ct = CT_all + (size_t)idx * NN * NN;
    for (int e = tid; e < NN * NN; e += 64) {
        int col = e >> 5, m2 = e & 31;
        ct[(size_t)rankl[col] * NN + m2] = (float)V[m2][col];
    }
}

// ---------------------------------------------------------------------------
// Phase A2: kk[b,s,j] = argmax_i S[b,s,i,j]^2  (first index on ties), where
// S = C_s^T C_{s-1}; with CT layout, S[i][j] = dot(CT_s row i, CT_{s-1} row j)
// ---------------------------------------------------------------------------
__global__ __launch_bounds__(256) void kk_kernel(const float* __restrict__ CT_all,
                                                 int* __restrict__ kk_all)
{
    __shared__ float Ct[NN][NN + 1], Cp[NN][NN + 1], S[NN][NN + 1];
    const int blk = blockIdx.x;                // b*600 + (s-1)
    const int b = blk / NSTEPS, s = blk % NSTEPS + 1;
    const int tid = threadIdx.x;
    const float* ctg = CT_all + ((size_t)b * NT1 + s) * (NN * NN);
    const float* cpg = CT_all + ((size_t)b * NT1 + s - 1) * (NN * NN);
    for (int e = tid; e < NN * NN; e += 256) {
        Ct[e >> 5][e & 31] = ctg[e];
        Cp[e >> 5][e & 31] = cpg[e];
    }
    __syncthreads();
    for (int e = tid; e < NN * NN; e += 256) {
        int i = e >> 5, j = e & 31;
        float acc = 0.f;
        for (int m = 0; m < NN; ++m) acc += Ct[i][m] * Cp[j][m];
        S[i][j] = acc;
    }
    __syncthreads();
    if (tid < NN) {
        const int j = tid;
        float best = -1.f; int bi = 0;
        for (int i = 0; i < NN; ++i) {
            float v = S[i][j]; v *= v;
            if (v > best) { best = v; bi = i; }
        }
        kk_all[(size_t)blk * NN + j] = bi;
    }
}

// transpose W2/W3 so the MLP inner loop reads contiguous wave-uniform rows
__global__ void wtrans_kernel(const float* __restrict__ W2, const float* __restrict__ W3,
                              float* __restrict__ W2T, float* __restrict__ W3T)
{
    const int tid = threadIdx.x;
    for (int e = tid; e < NH * NH; e += 256) {
        int u = e / NH, k = e % NH;
        W2T[k * NH + u] = W2[e];
        W3T[k * NH + u] = W3[e];
    }
}

// ---------------------------------------------------------------------------
// Phase B: one launch per time step t (1..600). Each launch:
//   prologue (all blocks of a batch element redundantly, bitwise identical):
//     completes step s=t-1 in FP64: CD/newval fix of S2_{t-1}, phase*matvec,
//     normalize, ploc/ps output, phi2 for this step's ratio feature.
//   main: S = C_t^T C_{t-1}, features, 8->75->75->75->1 ELU MLP (fp32),
//     S2_t store. grid (do_main): 256 blocks x 128 thr; thread = (i,j) row.
// S2 (fp32) and phiB (fp64) are parity double-buffered across launches.
// ---------------------------------------------------------------------------
__global__ __launch_bounds__(128) void step_kernel(
    const int t, const int do_main,
    const float* __restrict__ E_all, const float* __restrict__ CT_all,
    const int* __restrict__ kk_all, const float* __restrict__ psi0,
    const float* __restrict__ Tarr, const float* __restrict__ ErA,
    const float* __restrict__ ctA, const float* __restrict__ dtA,
    const float* __restrict__ W1, const float* __restrict__ b1,
    const float* __restrict__ W2T, const float* __restrict__ b2,
    const float* __restrict__ W3T, const float* __restrict__ b3,
    const float* __restrict__ W4, const float* __restrict__ b4v,
    float* __restrict__ S2_buf, double* __restrict__ phiB_buf,
    float* __restrict__ out)
{
    __shared__ float hbuf[NH][128];
    __shared__ float Cp[NN][NN + 1];
    __shared__ float Ct4[4][NN + 1];
    __shared__ float S2l[NN][NN + 1];
    __shared__ float EtL[NN], EpL[NN];
    __shared__ int   kkM[NN], kkP[NN];
    __shared__ double obre[NN], obim[NN];
    __shared__ double phre[NN], phim[NN], redl[NN];
    __shared__ float phi2l[NN];

    const int tid = threadIdx.x;
    const int b    = do_main ? (blockIdx.x >> 3) : blockIdx.x;
    const int iblk = do_main ? (blockIdx.x & 7) : 0;
    const int s = t - 1;   // step completed by the prologue

    // ---- staging ----
    const float* cpg = CT_all + ((size_t)b * NT1 + (t - 1)) * (NN * NN);
    for (int e = tid; e < NN * NN; e += 128) Cp[e >> 5][e & 31] = cpg[e];
    if (tid < NN) EpL[tid] = E_all[((size_t)b * NT1 + (t - 1)) * NN + tid];
    if (s >= 1) {
        const float* s2g = S2_buf + ((size_t)(s & 1) * NB + b) * (NN * NN);
        for (int e = tid; e < NN * NN; e += 128) S2l[e >> 5][e & 31] = s2g[e];
        if (tid < NN) kkP[tid] = kk_all[((size_t)b * NSTEPS + (s - 1)) * NN + tid];
        const double* pbo = phiB_buf + ((size_t)((s - 1) & 1) * NB + b) * (2 * NN);
        if (tid < NN) obre[tid] = pbo[tid];
        else if (tid < 2 * NN) obim[tid - NN] = pbo[tid];
    }
    if (do_main) {
        const float* ctg = CT_all + ((size_t)b * NT1 + t) * (NN * NN);
        Ct4[tid >> 5][tid & 31] = ctg[(iblk * 4 + (tid >> 5)) * NN + (tid & 31)];
        if (tid < NN) {
            EtL[tid] = E_all[((size_t)b * NT1 + t) * NN + tid];
            kkM[tid] = kk_all[((size_t)b * NSTEPS + (t - 1)) * NN + tid];
        }
    }
    __syncthreads();

    // ---- prologue ----
    if (s == 0) {
        if (tid < NN) {
            const int i = tid;
            double acc = 0.0;
            for (int j = 0; j < NN; ++j) acc += (double)Cp[i][j] * (double)psi0[(size_t)b * NN + j];
            phre[i] = acc; phim[i] = 0.0;
            phi2l[i] = (float)(acc * acc);
            float p0 = psi0[(size_t)b * NN + i];
            out[((size_t)b * 61) * NN + i] = p0 * p0;
            double* pb = phiB_buf + (size_t)b * (2 * NN);   // parity 0
            pb[i] = acc; pb[NN + i] = 0.0;
        }
        __syncthreads();
    } else {
        if (tid < NN) {          // per-column correction of S2_{s}
            const int j = tid;
            const int kj = kkP[j];
            double cd = 0.0;
            for (int i2 = 0; i2 < NN; ++i2) {
                double v = (double)S2l[i2][j];
                cd += (i2 == kj) ? 0.0 : v * v;
            }
            double skk = (double)S2l[kj][j];
            double nrm = fabs(skk); nrm = (nrm > 0.0) ? nrm : 1.0;
            double rem = 1.0 - cd;
            S2l[kj][j] = (float)((rem > 0.0) ? (sqrt(rem) * skk / nrm) : skk);
        }
        __syncthreads();
        if (tid < NN) {          // phiB <- phase * (S2' @ phiB)
            const int i = tid;
            double are = 0.0, aim = 0.0;
            for (int j = 0; j < NN; ++j) {
                double sv = (double)S2l[i][j];
                are += sv * obre[j];
                aim += sv * obim[j];
            }
            double th = (double)EpL[i] * (TWO_PI * ICM2IFS) * (double)dtA[b];
            double cph = cos(th), sph = sin(th);  // exp(-i E w) = c - i s
            double nre = cph * are + sph * aim;
            double nim = cph * aim - sph * are;
            phre[i] = nre; phim[i] = nim;
            redl[i] = nre * nre + nim * nim;
        }
        __syncthreads();
        if (tid < NN) {          // normalize, store carry, phi2
            double sum = 0.0;
            for (int j = 0; j < NN; ++j) sum += redl[j];
            double sc = 1.0 / sqrt(sum);
            double nre = phre[tid] * sc, nim = phim[tid] * sc;
            phre[tid] = nre; phim[tid] = nim;
            phi2l[tid] = (float)(nre * nre + nim * nim);
            double* pb = phiB_buf + ((size_t)(s & 1) * NB + b) * (2 * NN);
            pb[tid] = nre; pb[NN + tid] = nim;
        }
        __syncthreads();
        if (tid < NN) {          // ploc = C_s @ phiB ; ps output every NSI
            const int i = tid;
            double are = 0.0, aim = 0.0;
            for (int j = 0; j < NN; ++j) {
                double cij = (double)Cp[j][i];     // C_s[i][j] = CT_s[j][i]
                are += cij * phre[j];
                aim += cij * phim[j];
            }
            if ((s % NSI) == 0)
                out[((size_t)b * 61 + (s / NSI)) * NN + i] = (float)(are * are + aim * aim);
        }
        __syncthreads();
    }

    if (!do_main) return;

    // ---- main: features + MLP for step t (fp32) ----
    const int il = tid >> 5;
    const int i = iblk * 4 + il;
    const int j = tid & 31;
    const float kbt = KBOLTZ * Tarr[b];
    const float er = ErA[b];
    const float cti = ctA[b];

    float Sv = 0.f;
    for (int m = 0; m < NN; ++m) Sv += Ct4[il][m] * Cp[j][m];
    const int kj = kkM[j];
    const float DE = (i == kj) ? 0.f : (EtL[i] - EpL[j]);
    const float p_i = phi2l[i], p_j = phi2l[j];     // p_jj=phi2[i], p_ii=phi2[j]
    const bool msk = p_j > 0.01f * p_i;
    const float ratio = msk ? (p_i / p_j) : 100.f;
    const float ex = expf(DE / kbt);

    // layer 1 (8 -> 75): rolled; weights wave-uniform
    for (int u = 0; u < NH; ++u) {
        const float* w = W1 + u * 8;
        float pre = b1[u] + w[0] * DE + w[1] * ratio + w[2] * Sv + w[3] * kbt
                  + w[4] * er + w[5] * cti + w[7] * ex;   // feature 6 is zero
        hbuf[u][tid] = elu1(pre);
    }
    // layer 2 (75 -> 75): acc in VGPRs, h streamed from private LDS column
    float acc[NH];
    #pragma unroll
    for (int u = 0; u < NH; ++u) acc[u] = b2[u];
    for (int k = 0; k < NH; ++k) {
        const float hk = hbuf[k][tid];
        const float* w = W2T + k * NH;
        #pragma unroll
        for (int u = 0; u < NH; ++u) acc[u] += hk * w[u];
    }
    #pragma unroll
    for (int u = 0; u < NH; ++u) hbuf[u][tid] = elu1(acc[u]);
    // layer 3
    #pragma unroll
    for (int u = 0; u < NH; ++u) acc[u] = b3[u];
    for (int k = 0; k < NH; ++k) {
        const float hk = hbuf[k][tid];
        const float* w = W3T + k * NH;
        #pragma unroll
        for (int u = 0; u < NH; ++u) acc[u] += hk * w[u];
    }
    #pragma unroll
    for (int u = 0; u < NH; ++u) hbuf[u][tid] = elu1(acc[u]);
    // layer 4 (75 -> 1)
    float a4 = b4v[0];
    for (int k = 0; k < NH; ++k) a4 += hbuf[k][tid] * W4[k];
    const float corr = elu1(a4) + 1.f;

    float* s2o = S2_buf + ((size_t)(t & 1) * NB + b) * (NN * NN);
    s2o[i * NN + j] = Sv * corr;
}

// ---------------------------------------------------------------------------
extern "C" void kernel_launch(void* const* d_in, const int* in_sizes, int n_in,
                              void* d_out, int out_size, void* d_ws, size_t ws_size,
                              hipStream_t stream)
{
    const float* Tarr = (const float*)d_in[0];
    const float* ErA  = (const float*)d_in[1];
    const float* ctA  = (const float*)d_in[2];
    const float* dtA  = (const float*)d_in[4];
    const float* psi0 = (const float*)d_in[6];
    const float* Hf   = (const float*)d_in[7];
    const float* W1   = (const float*)d_in[8];
    const float* b1   = (const float*)d_in[9];
    const float* W2   = (const float*)d_in[10];
    const float* b2   = (const float*)d_in[11];
    const float* W3   = (const float*)d_in[12];
    const float* b3   = (const float*)d_in[13];
    const float* W4   = (const float*)d_in[14];
    const float* b4   = (const float*)d_in[15];

    // phiB (fp64) first so it inherits d_ws alignment
    double* phiB  = (double*)d_ws;                              // 2*32*64 doubles
    float* E_all  = (float*)(phiB + 2 * (size_t)NB * 2 * NN);   // 32*601*32
    float* CT_all = E_all + (size_t)NB * NT1 * NN;              // 32*601*32*32
    float* W2T    = CT_all + (size_t)NB * NT1 * NN * NN;        // 75*75
    float* W3T    = W2T + NH * NH;                              // 75*75
    float* S2_buf = W3T + NH * NH;                              // 2*32*32*32
    int*   kk_all = (int*)(S2_buf + 2 * (size_t)NB * NN * NN);  // 32*600*32

    eigh_kernel<<<NB * NT1, 64, 0, stream>>>(Hf, E_all, CT_all);
    wtrans_kernel<<<1, 256, 0, stream>>>(W2, W3, W2T, W3T);
    kk_kernel<<<NB * NSTEPS, 256, 0, stream>>>(CT_all, kk_all);

    for (int t = 1; t <= NSTEPS; ++t) {
        step_kernel<<<NB * 8, 128, 0, stream>>>(t, 1, E_all, CT_all, kk_all, psi0,
            Tarr, ErA, ctA, dtA, W1, b1, W2T, b2, W3T, b3, W4, b4,
            S2_buf, phiB, (float*)d_out);
    }
    // epilogue: complete step 600 (writes out row 60)
    step_kernel<<<NB, 128, 0, stream>>>(NSTEPS + 1, 0, E_all, CT_all, kk_all, psi0,
        Tarr, ErA, ctA, dtA, W1, b1, W2T, b2, W3T, b3, W4, b4,
        S2_buf, phiB, (float*)d_out);
}

// Round 3
// 44478.339 us; speedup vs baseline: 1.0184x; 1.0184x over previous
//
#include <hip/hip_runtime.h>
#include <math.h>

#define NB 32
#define NN 32
#define NSTEPS 600
#define NT1 601
#define NSI 10
#define NH 75
#define NHP 76   // padded MLP width (zero column) so both u-halves run 38 FMAs unguarded

#define ICM2IFS 2.99792458e-05
#define KBOLTZ 0.6950389f
#define TWO_PI 6.283185307179586476925286766559

// elu via native exp: |err| ~1e-7 absolute vs expm1 — negligible over 600 steps
__device__ __forceinline__ float elu1(float x) { return x > 0.f ? x : (__expf(x) - 1.f); }

// ---------------------------------------------------------------------------
// Phase A: batched 32x32 symmetric eigensolver (parallel cyclic Jacobi), FP64.
// One block (1 wave) per matrix. Cap 12 sweeps, tol 1e-24*||A||^2 (off-diag
// ~1e-12 rel — far below the fp32 rounding of the emitted vectors).
// ---------------------------------------------------------------------------
__global__ __launch_bounds__(64) void eigh_kernel(const float* __restrict__ Hf,
                                                  float* __restrict__ E_all,
                                                  float* __restrict__ CT_all)
{
    __shared__ double A[NN][NN + 1];
    __shared__ double V[NN][NN + 1];
    __shared__ double csC[16], csS[16];
    __shared__ int   prC[16], qrC[16];
    __shared__ double redv;
    __shared__ int   rankl[NN];

    const int idx = blockIdx.x;      // b*601 + t
    const int tid = threadIdx.x;
    const float* Hp = Hf + (size_t)idx * (NN * NN);

    for (int e = tid; e < NN * NN; e += 64) {
        A[e >> 5][e & 31] = (double)Hp[e];
        V[e >> 5][e & 31] = ((e >> 5) == (e & 31)) ? 1.0 : 0.0;
    }
    __syncthreads();

    double part = 0.0;
    for (int e = tid; e < NN * NN; e += 64) { double v = A[e >> 5][e & 31]; part += v * v; }
    #pragma unroll
    for (int off = 32; off > 0; off >>= 1) part += __shfl_down(part, off);
    if (tid == 0) redv = part;
    __syncthreads();
    const double tol2 = 1e-24 * redv;

    for (int sweep = 0; sweep < 12; ++sweep) {
        for (int r = 0; r < NN - 1; ++r) {
            if (tid < 16) {
                int m = tid, p, q;
                if (m == 0) { p = 0; q = 1 + (r % 31); }
                else { p = 1 + ((m + r) % 31); q = 1 + ((31 - m + r) % 31); }
                double apq = A[p][q];
                double c = 1.0, sn = 0.0;
                if (apq != 0.0) {
                    double theta = 0.5 * (A[q][q] - A[p][p]) / apq;
                    double tt = 1.0 / (fabs(theta) + sqrt(theta * theta + 1.0));
                    if (theta < 0.0) tt = -tt;
                    c = 1.0 / sqrt(tt * tt + 1.0);
                    sn = tt * c;
                }
                csC[m] = c; csS[m] = sn; prC[m] = p; qrC[m] = q;
            }
            __syncthreads();
            #pragma unroll
            for (int it = 0; it < 8; ++it) {          // rows: A <- J^T A
                int task = tid + it * 64;
                int m = task >> 5, jc = task & 31;
                int p = prC[m], q = qrC[m];
                double c = csC[m], sn = csS[m];
                double ap = A[p][jc], aq = A[q][jc];
                A[p][jc] = c * ap - sn * aq;
                A[q][jc] = sn * ap + c * aq;
            }
            __syncthreads();
            #pragma unroll
            for (int it = 0; it < 16; ++it) {         // cols: A <- A J, V <- V J
                int task = tid + it * 64;
                int m = (task >> 5) & 15, ir = task & 31;
                int p = prC[m], q = qrC[m];
                double c = csC[m], sn = csS[m];
                if (task < 512) {
                    double aip = A[ir][p], aiq = A[ir][q];
                    A[ir][p] = c * aip - sn * aiq;
                    A[ir][q] = sn * aip + c * aiq;
                } else {
                    double vip = V[ir][p], viq = V[ir][q];
                    V[ir][p] = c * vip - sn * viq;
                    V[ir][q] = sn * vip + c * viq;
                }
            }
            __syncthreads();
        }
        if (sweep >= 2) {
            double o = 0.0;
            for (int e = tid; e < NN * NN; e += 64) {
                int i2 = e >> 5, j2 = e & 31;
                double v = A[i2][j2];
                o += (i2 != j2) ? v * v : 0.0;
            }
            #pragma unroll
            for (int off = 32; off > 0; off >>= 1) o += __shfl_down(o, off);
            if (tid == 0) redv = o;
            __syncthreads();
            if (redv <= tol2) break;
        }
    }
    __syncthreads();

    if (tid < NN) {
        double ei = A[tid][tid];
        int rk = 0;
        for (int j2 = 0; j2 < NN; ++j2) {
            double ej = A[j2][j2];
            rk += (ej < ei || (ej == ei && j2 < tid)) ? 1 : 0;
        }
        rankl[tid] = rk;
        E_all[(size_t)idx * NN + rk] = (float)ei;
    }
    __syncthreads();
    float* ct = CT_all + (size_t)idx * NN * NN;
    for (int e = tid; e < NN * NN; e += 64) {
        int col = e >> 5, m2 = e & 31;
        ct[(size_t)rankl[col] * NN + m2] = (float)V[m2][col];
    }
}

// ---------------------------------------------------------------------------
// Phase A2: kk[b,s,j] = argmax_i S[b,s,i,j]^2 (first index on ties)
// ---------------------------------------------------------------------------
__global__ __launch_bounds__(256) void kk_kernel(const float* __restrict__ CT_all,
                                                 int* __restrict__ kk_all)
{
    __shared__ float Ct[NN][NN + 1], Cp[NN][NN + 1], S[NN][NN + 1];
    const int blk = blockIdx.x;                // b*600 + (s-1)
    const int b = blk / NSTEPS, s = blk % NSTEPS + 1;
    const int tid = threadIdx.x;
    const float* ctg = CT_all + ((size_t)b * NT1 + s) * (NN * NN);
    const float* cpg = CT_all + ((size_t)b * NT1 + s - 1) * (NN * NN);
    for (int e = tid; e < NN * NN; e += 256) {
        Ct[e >> 5][e & 31] = ctg[e];
        Cp[e >> 5][e & 31] = cpg[e];
    }
    __syncthreads();
    for (int e = tid; e < NN * NN; e += 256) {
        int i = e >> 5, j = e & 31;
        float acc = 0.f;
        for (int m = 0; m < NN; ++m) acc += Ct[i][m] * Cp[j][m];
        S[i][j] = acc;
    }
    __syncthreads();
    if (tid < NN) {
        const int j = tid;
        float best = -1.f; int bi = 0;
        for (int i = 0; i < NN; ++i) {
            float v = S[i][j]; v *= v;
            if (v > best) { best = v; bi = i; }
        }
        kk_all[(size_t)blk * NN + j] = bi;
    }
}

// transpose + pad weights: W2T/W3T are [75][76] (zero col 75); bpad packs
// b2[76] | b3[76] | W4[76], zero-padded.
__global__ void wtrans_kernel(const float* __restrict__ W2, const float* __restrict__ W3,
                              const float* __restrict__ b2, const float* __restrict__ b3,
                              const float* __restrict__ W4,
                              float* __restrict__ W2T, float* __restrict__ W3T,
                              float* __restrict__ bpad)
{
    const int tid = threadIdx.x;
    for (int e = tid; e < NH * NHP; e += 256) {
        int k = e / NHP, u = e % NHP;
        W2T[e] = (u < NH) ? W2[u * NH + k] : 0.f;
        W3T[e] = (u < NH) ? W3[u * NH + k] : 0.f;
    }
    if (tid < NHP) {
        bpad[tid]           = (tid < NH) ? b2[tid] : 0.f;
        bpad[NHP + tid]     = (tid < NH) ? b3[tid] : 0.f;
        bpad[2 * NHP + tid] = (tid < NH) ? W4[tid] : 0.f;
    }
}

// ---------------------------------------------------------------------------
// Phase B: one launch per step t. 256 blocks x 256 threads (do_main):
// block = (b, iblk): rows i in [iblk*4, iblk*4+4) x j in [0,32) = 128 rows.
// Each row is handled by TWO waves (u-halves): w = tid>>6, row = (w&1)*64 +
// (tid&63), tau = w>>1, U0 = tau*38. Weight bases are wave-uniform -> s_load;
// h round-trips through hbuf[76][128] (2-way banks = free).
// Prologue (fp64, wave 0, duplicated per iblk-block) completes step t-1.
// ---------------------------------------------------------------------------
__global__ __launch_bounds__(256) void step_kernel(
    const int t, const int do_main,
    const float* __restrict__ E_all, const float* __restrict__ CT_all,
    const int* __restrict__ kk_all, const float* __restrict__ psi0,
    const float* __restrict__ Tarr, const float* __restrict__ ErA,
    const float* __restrict__ ctA, const float* __restrict__ dtA,
    const float* __restrict__ W1, const float* __restrict__ b1,
    const float* __restrict__ W2T, const float* __restrict__ W3T,
    const float* __restrict__ bpad, const float* __restrict__ b4v,
    float* __restrict__ S2_buf, double* __restrict__ phiB_buf,
    float* __restrict__ out)
{
    __shared__ float hbuf[NHP][128];
    __shared__ float a4buf[2][128];
    __shared__ float Cp[NN][NN + 1];
    __shared__ float Ct4[4][NN + 1];
    __shared__ float S2l[NN][NN + 1];
    __shared__ float EtL[NN], EpL[NN];
    __shared__ int   kkM[NN], kkP[NN];
    __shared__ double obre[NN], obim[NN];
    __shared__ double phre[NN], phim[NN], redl[NN];
    __shared__ float phi2l[NN];

    const int tid = threadIdx.x;
    const int b    = do_main ? (blockIdx.x >> 3) : blockIdx.x;
    const int iblk = do_main ? (blockIdx.x & 7) : 0;
    const int s = t - 1;   // step completed by the prologue

    // ---- staging ----
    const float* cpg = CT_all + ((size_t)b * NT1 + (t - 1)) * (NN * NN);
    for (int e = tid; e < NN * NN; e += 256) Cp[e >> 5][e & 31] = cpg[e];
    if (tid < NN) EpL[tid] = E_all[((size_t)b * NT1 + (t - 1)) * NN + tid];
    if (s >= 1) {
        const float* s2g = S2_buf + ((size_t)(s & 1) * NB + b) * (NN * NN);
        for (int e = tid; e < NN * NN; e += 256) S2l[e >> 5][e & 31] = s2g[e];
        if (tid < NN) kkP[tid] = kk_all[((size_t)b * NSTEPS + (s - 1)) * NN + tid];
        const double* pbo = phiB_buf + ((size_t)((s - 1) & 1) * NB + b) * (2 * NN);
        if (tid < NN) obre[tid] = pbo[tid];
        else if (tid < 2 * NN) obim[tid - NN] = pbo[tid];
    }
    if (do_main) {
        const float* ctg = CT_all + ((size_t)b * NT1 + t) * (NN * NN);
        if (tid < 128) Ct4[tid >> 5][tid & 31] = ctg[(iblk * 4 + (tid >> 5)) * NN + (tid & 31)];
        if (tid < NN) {
            EtL[tid] = E_all[((size_t)b * NT1 + t) * NN + tid];
            kkM[tid] = kk_all[((size_t)b * NSTEPS + (t - 1)) * NN + tid];
        }
    }
    __syncthreads();

    // ---- prologue (fp64) ----
    if (s == 0) {
        if (tid < NN) {
            const int i = tid;
            double acc = 0.0;
            for (int j = 0; j < NN; ++j) acc += (double)Cp[i][j] * (double)psi0[(size_t)b * NN + j];
            phre[i] = acc; phim[i] = 0.0;
            phi2l[i] = (float)(acc * acc);
            float p0 = psi0[(size_t)b * NN + i];
            out[((size_t)b * 61) * NN + i] = p0 * p0;
            double* pb = phiB_buf + (size_t)b * (2 * NN);   // parity 0
            pb[i] = acc; pb[NN + i] = 0.0;
        }
        __syncthreads();
    } else {
        if (tid < NN) {          // per-column correction of S2_s
            const int j = tid;
            const int kj = kkP[j];
            double cd = 0.0;
            for (int i2 = 0; i2 < NN; ++i2) {
                double v = (double)S2l[i2][j];
                cd += (i2 == kj) ? 0.0 : v * v;
            }
            double skk = (double)S2l[kj][j];
            double nrm = fabs(skk); nrm = (nrm > 0.0) ? nrm : 1.0;
            double rem = 1.0 - cd;
            S2l[kj][j] = (float)((rem > 0.0) ? (sqrt(rem) * skk / nrm) : skk);
        }
        __syncthreads();
        if (tid < NN) {          // phiB <- phase * (S2' @ phiB)
            const int i = tid;
            double are = 0.0, aim = 0.0;
            for (int j = 0; j < NN; ++j) {
                double sv = (double)S2l[i][j];
                are += sv * obre[j];
                aim += sv * obim[j];
            }
            double th = (double)EpL[i] * (TWO_PI * ICM2IFS) * (double)dtA[b];
            double cph = cos(th), sph = sin(th);  // exp(-i E w) = c - i s
            double nre = cph * are + sph * aim;
            double nim = cph * aim - sph * are;
            phre[i] = nre; phim[i] = nim;
            redl[i] = nre * nre + nim * nim;
        }
        __syncthreads();
        if (tid < NN) {          // normalize, store carry, phi2
            double sum = 0.0;
            for (int j = 0; j < NN; ++j) sum += redl[j];
            double sc = 1.0 / sqrt(sum);
            double nre = phre[tid] * sc, nim = phim[tid] * sc;
            phre[tid] = nre; phim[tid] = nim;
            phi2l[tid] = (float)(nre * nre + nim * nim);
            double* pb = phiB_buf + ((size_t)(s & 1) * NB + b) * (2 * NN);
            pb[tid] = nre; pb[NN + tid] = nim;
        }
        __syncthreads();
        if (tid < NN) {          // ploc = C_s @ phiB ; ps output every NSI
            const int i = tid;
            double are = 0.0, aim = 0.0;
            for (int j = 0; j < NN; ++j) {
                double cij = (double)Cp[j][i];
                are += cij * phre[j];
                aim += cij * phim[j];
            }
            if ((s % NSI) == 0)
                out[((size_t)b * 61 + (s / NSI)) * NN + i] = (float)(are * are + aim * aim);
        }
        __syncthreads();
    }

    if (!do_main) return;

    // ---- main: features + split-wave MLP for step t (fp32) ----
    const int w    = tid >> 6;
    const int row  = ((w & 1) << 6) | (tid & 63);  // 0..127
    const int tau  = w >> 1;                        // u-half
    const int U0   = tau * 38;
    const int il = row >> 5;
    const int i = iblk * 4 + il;
    const int j = row & 31;
    const float kbt = KBOLTZ * Tarr[b];
    const float er = ErA[b];
    const float cti = ctA[b];
    const float* b2p = bpad;
    const float* b3p = bpad + NHP;
    const float* W4p = bpad + 2 * NHP;

    float Sv = 0.f;
    for (int m = 0; m < NN; ++m) Sv += Ct4[il][m] * Cp[j][m];
    const int kj = kkM[j];
    const float DE = (i == kj) ? 0.f : (EtL[i] - EpL[j]);
    const float p_i = phi2l[i], p_j = phi2l[j];
    const bool msk = p_j > 0.01f * p_i;
    const float ratio = msk ? (p_i / p_j) : 100.f;
    const float ex = __expf(DE / kbt);

    // layer 1 (8 -> 75): this wave computes its u-half
    for (int uu = 0; uu < 38; ++uu) {
        const int u = U0 + uu;
        if (u < NH) {
            const float* wp = W1 + u * 8;
            float pre = b1[u] + wp[0] * DE + wp[1] * ratio + wp[2] * Sv + wp[3] * kbt
                      + wp[4] * er + wp[5] * cti + wp[7] * ex;   // feature 6 is zero
            hbuf[u][row] = elu1(pre);
        } else hbuf[u][row] = 0.f;
    }
    __syncthreads();

    float acc[38];
    // layer 2 (75 -> 75, half-width per wave)
    #pragma unroll
    for (int uu = 0; uu < 38; ++uu) acc[uu] = b2p[U0 + uu];
    for (int k = 0; k < NH; ++k) {
        const float hk = hbuf[k][row];
        const float* wp = W2T + k * NHP + U0;    // wave-uniform -> s_load
        #pragma unroll
        for (int uu = 0; uu < 38; ++uu) acc[uu] += hk * wp[uu];
    }
    __syncthreads();
    #pragma unroll
    for (int uu = 0; uu < 38; ++uu) hbuf[U0 + uu][row] = elu1(acc[uu]);
    __syncthreads();
    // layer 3
    #pragma unroll
    for (int uu = 0; uu < 38; ++uu) acc[uu] = b3p[U0 + uu];
    for (int k = 0; k < NH; ++k) {
        const float hk = hbuf[k][row];
        const float* wp = W3T + k * NHP + U0;
        #pragma unroll
        for (int uu = 0; uu < 38; ++uu) acc[uu] += hk * wp[uu];
    }
    __syncthreads();
    #pragma unroll
    for (int uu = 0; uu < 38; ++uu) hbuf[U0 + uu][row] = elu1(acc[uu]);
    __syncthreads();
    // layer 4 (75 -> 1): each wave dots its half, combine via LDS
    float a4p = 0.f;
    #pragma unroll
    for (int uu = 0; uu < 38; ++uu) a4p += hbuf[U0 + uu][row] * W4p[U0 + uu];
    a4buf[tau][row] = a4p;
    __syncthreads();
    if (w < 2) {
        const float a4 = b4v[0] + a4buf[0][row] + a4buf[1][row];
        const float corr = elu1(a4) + 1.f;
        float* s2o = S2_buf + ((size_t)(t & 1) * NB + b) * (NN * NN);
        s2o[i * NN + j] = Sv * corr;
    }
}

// ---------------------------------------------------------------------------
extern "C" void kernel_launch(void* const* d_in, const int* in_sizes, int n_in,
                              void* d_out, int out_size, void* d_ws, size_t ws_size,
                              hipStream_t stream)
{
    const float* Tarr = (const float*)d_in[0];
    const float* ErA  = (const float*)d_in[1];
    const float* ctA  = (const float*)d_in[2];
    const float* dtA  = (const float*)d_in[4];
    const float* psi0 = (const float*)d_in[6];
    const float* Hf   = (const float*)d_in[7];
    const float* W1   = (const float*)d_in[8];
    const float* b1   = (const float*)d_in[9];
    const float* W2   = (const float*)d_in[10];
    const float* b2   = (const float*)d_in[11];
    const float* W3   = (const float*)d_in[12];
    const float* b3   = (const float*)d_in[13];
    const float* W4   = (const float*)d_in[14];
    const float* b4   = (const float*)d_in[15];

    // phiB (fp64) first so it inherits d_ws alignment
    double* phiB  = (double*)d_ws;                              // 2*32*64 doubles
    float* E_all  = (float*)(phiB + 2 * (size_t)NB * 2 * NN);   // 32*601*32
    float* CT_all = E_all + (size_t)NB * NT1 * NN;              // 32*601*32*32
    float* W2T    = CT_all + (size_t)NB * NT1 * NN * NN;        // 75*76
    float* W3T    = W2T + NH * NHP;                             // 75*76
    float* bpad   = W3T + NH * NHP;                             // 3*76
    float* S2_buf = bpad + 3 * NHP;                             // 2*32*32*32
    int*   kk_all = (int*)(S2_buf + 2 * (size_t)NB * NN * NN);  // 32*600*32

    eigh_kernel<<<NB * NT1, 64, 0, stream>>>(Hf, E_all, CT_all);
    wtrans_kernel<<<1, 256, 0, stream>>>(W2, W3, b2, b3, W4, W2T, W3T, bpad);
    kk_kernel<<<NB * NSTEPS, 256, 0, stream>>>(CT_all, kk_all);

    for (int t = 1; t <= NSTEPS; ++t) {
        step_kernel<<<NB * 8, 256, 0, stream>>>(t, 1, E_all, CT_all, kk_all, psi0,
            Tarr, ErA, ctA, dtA, W1, b1, W2T, W3T, bpad, b4,
            S2_buf, phiB, (float*)d_out);
    }
    // epilogue: complete step 600 (writes out row 60)
    step_kernel<<<NB, 256, 0, stream>>>(NSTEPS + 1, 0, E_all, CT_all, kk_all, psi0,
        Tarr, ErA, ctA, dtA, W1, b1, W2T, W3T, bpad, b4,
        S2_buf, phiB, (float*)d_out);
}

// Round 6
// 28010.275 us; speedup vs baseline: 1.6171x; 1.5879x over previous
//
#include <hip/hip_runtime.h>
#include <math.h>

#define NB 32
#define NN 32
#define NSTEPS 600
#define NT1 601
#define NSI 10
#define NH 75
#define NHP 76   // padded MLP width = 2*38 (zero col) so both u-halves run unguarded

#define ICM2IFS 2.99792458e-05
#define KBOLTZ 0.6950389f
#define TWO_PI 6.283185307179586476925286766559

__device__ __forceinline__ float elu1(float x) { return x > 0.f ? x : (__expf(x) - 1.f); }

// ---------------------------------------------------------------------------
// Phase A: batched 32x32 symmetric eigensolver (parallel cyclic Jacobi), FP64.
// ---------------------------------------------------------------------------
__global__ __launch_bounds__(64) void eigh_kernel(const float* __restrict__ Hf,
                                                  float* __restrict__ E_all,
                                                  float* __restrict__ CT_all)
{
    __shared__ double A[NN][NN + 1];
    __shared__ double V[NN][NN + 1];
    __shared__ double csC[16], csS[16];
    __shared__ int   prC[16], qrC[16];
    __shared__ double redv;
    __shared__ int   rankl[NN];

    const int idx = blockIdx.x;      // b*601 + t
    const int tid = threadIdx.x;
    const float* Hp = Hf + (size_t)idx * (NN * NN);

    for (int e = tid; e < NN * NN; e += 64) {
        A[e >> 5][e & 31] = (double)Hp[e];
        V[e >> 5][e & 31] = ((e >> 5) == (e & 31)) ? 1.0 : 0.0;
    }
    __syncthreads();

    double part = 0.0;
    for (int e = tid; e < NN * NN; e += 64) { double v = A[e >> 5][e & 31]; part += v * v; }
    #pragma unroll
    for (int off = 32; off > 0; off >>= 1) part += __shfl_down(part, off);
    if (tid == 0) redv = part;
    __syncthreads();
    const double tol2 = 1e-24 * redv;

    for (int sweep = 0; sweep < 12; ++sweep) {
        for (int r = 0; r < NN - 1; ++r) {
            if (tid < 16) {
                int m = tid, p, q;
                if (m == 0) { p = 0; q = 1 + (r % 31); }
                else { p = 1 + ((m + r) % 31); q = 1 + ((31 - m + r) % 31); }
                double apq = A[p][q];
                double c = 1.0, sn = 0.0;
                if (apq != 0.0) {
                    double theta = 0.5 * (A[q][q] - A[p][p]) / apq;
                    double tt = 1.0 / (fabs(theta) + sqrt(theta * theta + 1.0));
                    if (theta < 0.0) tt = -tt;
                    c = 1.0 / sqrt(tt * tt + 1.0);
                    sn = tt * c;
                }
                csC[m] = c; csS[m] = sn; prC[m] = p; qrC[m] = q;
            }
            __syncthreads();
            #pragma unroll
            for (int it = 0; it < 8; ++it) {          // rows: A <- J^T A
                int task = tid + it * 64;
                int m = task >> 5, jc = task & 31;
                int p = prC[m], q = qrC[m];
                double c = csC[m], sn = csS[m];
                double ap = A[p][jc], aq = A[q][jc];
                A[p][jc] = c * ap - sn * aq;
                A[q][jc] = sn * ap + c * aq;
            }
            __syncthreads();
            #pragma unroll
            for (int it = 0; it < 16; ++it) {         // cols: A <- A J, V <- V J
                int task = tid + it * 64;
                int m = (task >> 5) & 15, ir = task & 31;
                int p = prC[m], q = qrC[m];
                double c = csC[m], sn = csS[m];
                if (task < 512) {
                    double aip = A[ir][p], aiq = A[ir][q];
                    A[ir][p] = c * aip - sn * aiq;
                    A[ir][q] = sn * aip + c * aiq;
                } else {
                    double vip = V[ir][p], viq = V[ir][q];
                    V[ir][p] = c * vip - sn * viq;
                    V[ir][q] = sn * vip + c * viq;
                }
            }
            __syncthreads();
        }
        if (sweep >= 2) {
            double o = 0.0;
            for (int e = tid; e < NN * NN; e += 64) {
                int i2 = e >> 5, j2 = e & 31;
                double v = A[i2][j2];
                o += (i2 != j2) ? v * v : 0.0;
            }
            #pragma unroll
            for (int off = 32; off > 0; off >>= 1) o += __shfl_down(o, off);
            if (tid == 0) redv = o;
            __syncthreads();
            if (redv <= tol2) break;
        }
    }
    __syncthreads();

    if (tid < NN) {
        double ei = A[tid][tid];
        int rk = 0;
        for (int j2 = 0; j2 < NN; ++j2) {
            double ej = A[j2][j2];
            rk += (ej < ei || (ej == ei && j2 < tid)) ? 1 : 0;
        }
        rankl[tid] = rk;
        E_all[(size_t)idx * NN + rk] = (float)ei;
    }
    __syncthreads();
    float* ct = CT_all + (size_t)idx * NN * NN;
    for (int e = tid; e < NN * NN; e += 64) {
        int col = e >> 5, m2 = e & 31;
        ct[(size_t)rankl[col] * NN + m2] = (float)V[m2][col];
    }
}

// ---------------------------------------------------------------------------
// Phase A2: kk[b,s,j] = argmax_i S[b,s,i,j]^2 (first index on ties)
// ---------------------------------------------------------------------------
__global__ __launch_bounds__(256) void kk_kernel(const float* __restrict__ CT_all,
                                                 int* __restrict__ kk_all)
{
    __shared__ float Ct[NN][NN + 1], Cp[NN][NN + 1], S[NN][NN + 1];
    const int blk = blockIdx.x;                // b*600 + (s-1)
    const int b = blk / NSTEPS, s = blk % NSTEPS + 1;
    const int tid = threadIdx.x;
    const float* ctg = CT_all + ((size_t)b * NT1 + s) * (NN * NN);
    const float* cpg = CT_all + ((size_t)b * NT1 + s - 1) * (NN * NN);
    for (int e = tid; e < NN * NN; e += 256) {
        Ct[e >> 5][e & 31] = ctg[e];
        Cp[e >> 5][e & 31] = cpg[e];
    }
    __syncthreads();
    for (int e = tid; e < NN * NN; e += 256) {
        int i = e >> 5, j = e & 31;
        float acc = 0.f;
        for (int m = 0; m < NN; ++m) acc += Ct[i][m] * Cp[j][m];
        S[i][j] = acc;
    }
    __syncthreads();
    if (tid < NN) {
        const int j = tid;
        float best = -1.f; int bi = 0;
        for (int i = 0; i < NN; ++i) {
            float v = S[i][j]; v *= v;
            if (v > best) { best = v; bi = i; }
        }
        kk_all[(size_t)blk * NN + j] = bi;
    }
}

// transpose + pad: W2T/W3T are [75][76] (zero col 75); bpad = b2[76]|b3[76]|W4[76]
__global__ void wtrans_kernel(const float* __restrict__ W2, const float* __restrict__ W3,
                              const float* __restrict__ b2, const float* __restrict__ b3,
                              const float* __restrict__ W4,
                              float* __restrict__ W2T, float* __restrict__ W3T,
                              float* __restrict__ bpad)
{
    const int tid = threadIdx.x;
    for (int e = tid; e < NH * NHP; e += 256) {
        int k = e / NHP, u = e % NHP;
        W2T[e] = (u < NH) ? W2[u * NH + k] : 0.f;
        W3T[e] = (u < NH) ? W3[u * NH + k] : 0.f;
    }
    if (tid < NHP) {
        bpad[tid]           = (tid < NH) ? b2[tid] : 0.f;
        bpad[NHP + tid]     = (tid < NH) ? b3[tid] : 0.f;
        bpad[2 * NHP + tid] = (tid < NH) ? W4[tid] : 0.f;
    }
}

// ---------------------------------------------------------------------------
// Phase B: ONE persistent (NON-cooperative) kernel, 256 blocks x 256 thr.
// Only the 8 sibling blocks of one batch element b ever communicate; they
// sync via a per-(b,step) counter barrier (release add / acquire spin,
// device scope). Deadlock-free by CAPACITY: LDS ~53 KB + VGPR<=256
// (__launch_bounds__(256,2)) => >=2 blocks/CU capacity => all 256 blocks of
// the grid are co-resident on 256 CUs no matter how dispatch packs them.
// Block numbering blk = iblk*32 + b => all 8 siblings of b are congruent
// mod 8 (same XCD under round-robin; perf heuristic only).
// Per step t: stage C_t/E/kk -> MLP_t -> write S2_t -> sibling barrier ->
//   column-correct S2_t, phiB <- phase(E_t)*(S2'@phiB) (fp64, replicated
//   identically per block), normalize, phi2, ps output every NSI (iblk==0).
// ---------------------------------------------------------------------------
__global__ __launch_bounds__(256, 2) void persist_kernel(
    const float* __restrict__ E_all, const float* __restrict__ CT_all,
    const int* __restrict__ kk_all, const float* __restrict__ psi0,
    const float* __restrict__ Tarr, const float* __restrict__ ErA,
    const float* __restrict__ ctA, const float* __restrict__ dtA,
    const float* __restrict__ W1, const float* __restrict__ b1,
    const float* __restrict__ W2T, const float* __restrict__ W3T,
    const float* __restrict__ bpad, const float* __restrict__ b4v,
    float* __restrict__ S2_g, unsigned int* __restrict__ cnt,
    float* __restrict__ out)
{
    __shared__ float CpN[2][NN][NN + 1];   // ping-pong C^T tiles
    __shared__ float hbuf[NHP][128];
    __shared__ float a4buf[2][128];
    __shared__ float S2l[NN][NN + 1];
    __shared__ float EtL[NN], EpL[NN];
    __shared__ int   kkM[NN];
    __shared__ double phre[NN], phim[NN], redl[NN];
    __shared__ float phi2l[NN];

    const int tid  = threadIdx.x;
    const int b    = blockIdx.x & 31;      // siblings: b, 32+b, ..., 224+b
    const int iblk = blockIdx.x >> 5;
    const int i0   = iblk * 4;
    const int w    = tid >> 6;
    const int row  = ((w & 1) << 6) | (tid & 63);   // 0..127
    const int U0   = __builtin_amdgcn_readfirstlane(w >> 1) * 38;  // uniform -> s_load

    const float kbt = KBOLTZ * Tarr[b];
    const float er  = ErA[b];
    const float cti = ctA[b];
    const double dtb = (double)dtA[b];

    // ---- init: C_0, phiB0 = C_0^T psi0, phi2, out row 0 ----
    {
        const float* c0g = CT_all + (size_t)b * NT1 * NN * NN;
        for (int e = tid; e < NN * NN; e += 256) CpN[0][e >> 5][e & 31] = c0g[e];
        __syncthreads();
        if (tid < NN) {
            const int i = tid;
            double acc = 0.0;
            for (int j = 0; j < NN; ++j) acc += (double)CpN[0][i][j] * (double)psi0[b * NN + j];
            phre[i] = acc; phim[i] = 0.0;
            phi2l[i] = (float)(acc * acc);
            if (iblk == 0) {
                float p0 = psi0[b * NN + i];
                out[((size_t)b * 61) * NN + i] = p0 * p0;
            }
        }
    }

    for (int t = 1; t <= NSTEPS; ++t) {
        __syncthreads();
        const int cur = t & 1;
        // ---- stage ----
        {
            const float* ctg = CT_all + ((size_t)b * NT1 + t) * (NN * NN);
            for (int e = tid; e < NN * NN; e += 256) CpN[cur][e >> 5][e & 31] = ctg[e];
            if (tid < NN) {
                EpL[tid] = E_all[((size_t)b * NT1 + t - 1) * NN + tid];
                EtL[tid] = E_all[((size_t)b * NT1 + t) * NN + tid];
                kkM[tid] = kk_all[((size_t)b * NSTEPS + t - 1) * NN + tid];
            }
        }
        __syncthreads();

        // ---- MLP for step t ----
        const int il = row >> 5;
        const int i  = i0 + il;
        const int j  = row & 31;
        const float (*Ct)[NN + 1] = CpN[cur];
        const float (*Cp)[NN + 1] = CpN[1 - cur];
        float Sv = 0.f;
        for (int m = 0; m < NN; ++m) Sv += Ct[i][m] * Cp[j][m];
        const int kj = kkM[j];
        const float DE = (i == kj) ? 0.f : (EtL[i] - EpL[j]);
        const float p_i = phi2l[i], p_j = phi2l[j];
        const float ratio = (p_j > 0.01f * p_i) ? (p_i / p_j) : 100.f;
        const float ex = __expf(DE / kbt);

        for (int uu = 0; uu < 38; ++uu) {              // layer 1 (8 -> 75)
            const int u = U0 + uu;
            float hv = 0.f;
            if (u < NH) {
                const float* wp = W1 + u * 8;
                float pre = b1[u] + wp[0] * DE + wp[1] * ratio + wp[2] * Sv + wp[3] * kbt
                          + wp[4] * er + wp[5] * cti + wp[7] * ex;   // feature 6 is zero
                hv = elu1(pre);
            }
            hbuf[u][row] = hv;
        }
        __syncthreads();

        float acc[38];
        #pragma unroll
        for (int uu = 0; uu < 38; ++uu) acc[uu] = bpad[U0 + uu];         // b2
        for (int k = 0; k < NH; ++k) {                 // layer 2
            const float hk = hbuf[k][row];
            const float* wp = W2T + k * NHP + U0;      // uniform base -> s_load
            #pragma unroll
            for (int uu = 0; uu < 38; ++uu) acc[uu] += hk * wp[uu];
        }
        __syncthreads();
        #pragma unroll
        for (int uu = 0; uu < 38; ++uu) hbuf[U0 + uu][row] = elu1(acc[uu]);
        __syncthreads();
        #pragma unroll
        for (int uu = 0; uu < 38; ++uu) acc[uu] = bpad[NHP + U0 + uu];   // b3
        for (int k = 0; k < NH; ++k) {                 // layer 3
            const float hk = hbuf[k][row];
            const float* wp = W3T + k * NHP + U0;
            #pragma unroll
            for (int uu = 0; uu < 38; ++uu) acc[uu] += hk * wp[uu];
        }
        __syncthreads();
        #pragma unroll
        for (int uu = 0; uu < 38; ++uu) hbuf[U0 + uu][row] = elu1(acc[uu]);
        __syncthreads();
        float a4p = 0.f;                               // layer 4 (75 -> 1)
        #pragma unroll
        for (int uu = 0; uu < 38; ++uu) a4p += hbuf[U0 + uu][row] * bpad[2 * NHP + U0 + uu];
        a4buf[w >> 1][row] = a4p;
        __syncthreads();
        if (w < 2) {
            const float a4 = b4v[0] + a4buf[0][row] + a4buf[1][row];
            const float corr = elu1(a4) + 1.f;
            S2_g[(((size_t)cur * NB + b) * NN + i) * NN + j] = Sv * corr;
            __threadfence();                           // make S2 agent-visible
        }
        __syncthreads();                               // stores+fences done block-wide

        // ---- sibling barrier (8 blocks of this b), per-step counter ----
        if (tid == 0) {
            unsigned int* c = cnt + (size_t)b * NSTEPS + (t - 1);
            __hip_atomic_fetch_add(c, 1u, __ATOMIC_RELEASE, __HIP_MEMORY_SCOPE_AGENT);
            while (__hip_atomic_load(c, __ATOMIC_ACQUIRE, __HIP_MEMORY_SCOPE_AGENT) < 8u)
                __builtin_amdgcn_s_sleep(2);
        }
        __syncthreads();

        // ---- complete step t (replicated per block, fp64) ----
        {
            const float* s2src = S2_g + ((size_t)cur * NB + b) * (NN * NN);
            for (int e = tid; e < NN * NN; e += 256) S2l[e >> 5][e & 31] = s2src[e];
        }
        __syncthreads();
        if (tid < NN) {                 // column correction (kk = kk_all[t-1])
            const int jj = tid;
            const int kj2 = kkM[jj];
            double cd = 0.0;
            for (int i2 = 0; i2 < NN; ++i2) {
                double v = (double)S2l[i2][jj];
                cd += (i2 == kj2) ? 0.0 : v * v;
            }
            double skk = (double)S2l[kj2][jj];
            double nrm = fabs(skk); nrm = (nrm > 0.0) ? nrm : 1.0;
            double rem = 1.0 - cd;
            S2l[kj2][jj] = (float)((rem > 0.0) ? (sqrt(rem) * skk / nrm) : skk);
        }
        __syncthreads();
        double nre = 0.0, nim = 0.0;
        if (tid < NN) {                 // phiB <- phase(E_t) * (S2' @ phiB)
            const int ii = tid;
            double are = 0.0, aim = 0.0;
            for (int jj = 0; jj < NN; ++jj) {
                double sv = (double)S2l[ii][jj];
                are += sv * phre[jj];
                aim += sv * phim[jj];
            }
            double th = (double)EtL[ii] * (TWO_PI * ICM2IFS) * dtb;   // |th| < ~0.1
            double x2 = th * th;        // poly sincos, |err| ~1e-16 at this range
            double sph = th * (1.0 + x2 * (-1.0 / 6.0 + x2 * (1.0 / 120.0 + x2 * (-1.0 / 5040.0 + x2 * (1.0 / 362880.0)))));
            double cph = 1.0 + x2 * (-0.5 + x2 * (1.0 / 24.0 + x2 * (-1.0 / 720.0 + x2 * (1.0 / 40320.0))));
            nre = cph * are + sph * aim;            // exp(-iEw) = c - i s
            nim = cph * aim - sph * are;
            redl[ii] = nre * nre + nim * nim;
        }
        __syncthreads();
        if (tid < NN) {                 // normalize, update carry + phi2
            double sum = 0.0;
            for (int jj = 0; jj < NN; ++jj) sum += redl[jj];
            double sc = 1.0 / sqrt(sum);
            nre *= sc; nim *= sc;
            phre[tid] = nre; phim[tid] = nim;
            phi2l[tid] = (float)(nre * nre + nim * nim);
        }
        __syncthreads();
        if ((t % NSI) == 0 && iblk == 0 && tid < NN) {   // ploc = C_t @ phiB
            const int ii = tid;
            double are = 0.0, aim = 0.0;
            for (int jj = 0; jj < NN; ++jj) {
                double cij = (double)CpN[cur][jj][ii];   // C_t[i][j] = CT_t[j][i]
                are += cij * phre[jj];
                aim += cij * phim[jj];
            }
            out[((size_t)b * 61 + t / NSI) * NN + ii] = (float)(are * are + aim * aim);
        }
    }
}

// ---------------------------------------------------------------------------
extern "C" void kernel_launch(void* const* d_in, const int* in_sizes, int n_in,
                              void* d_out, int out_size, void* d_ws, size_t ws_size,
                              hipStream_t stream)
{
    const float* Tarr = (const float*)d_in[0];
    const float* ErA  = (const float*)d_in[1];
    const float* ctA  = (const float*)d_in[2];
    const float* dtA  = (const float*)d_in[4];
    const float* psi0 = (const float*)d_in[6];
    const float* Hf   = (const float*)d_in[7];
    const float* W1   = (const float*)d_in[8];
    const float* b1   = (const float*)d_in[9];
    const float* W2   = (const float*)d_in[10];
    const float* b2   = (const float*)d_in[11];
    const float* W3   = (const float*)d_in[12];
    const float* b3   = (const float*)d_in[13];
    const float* W4   = (const float*)d_in[14];
    const float* b4   = (const float*)d_in[15];

    unsigned int* cnt = (unsigned int*)d_ws;                    // 32*600 counters
    float* E_all  = (float*)(cnt + (size_t)NB * NSTEPS);        // 32*601*32
    float* CT_all = E_all + (size_t)NB * NT1 * NN;              // 32*601*32*32
    float* W2T    = CT_all + (size_t)NB * NT1 * NN * NN;        // 75*76
    float* W3T    = W2T + NH * NHP;                             // 75*76
    float* bpad   = W3T + NH * NHP;                             // 3*76
    float* S2_g   = bpad + 3 * NHP;                             // 2*32*32*32
    int*   kk_all = (int*)(S2_g + 2 * (size_t)NB * NN * NN);    // 32*600*32
    float* outp   = (float*)d_out;

    hipMemsetAsync(cnt, 0, (size_t)NB * NSTEPS * sizeof(unsigned int), stream);
    eigh_kernel<<<NB * NT1, 64, 0, stream>>>(Hf, E_all, CT_all);
    wtrans_kernel<<<1, 256, 0, stream>>>(W2, W3, b2, b3, W4, W2T, W3T, bpad);
    kk_kernel<<<NB * NSTEPS, 256, 0, stream>>>(CT_all, kk_all);

    persist_kernel<<<NB * 8, 256, 0, stream>>>(E_all, CT_all, kk_all, psi0,
        Tarr, ErA, ctA, dtA, W1, b1, W2T, W3T, bpad, b4, S2_g, cnt, outp);
}